// Round 1
// baseline (233.671 us; speedup 1.0000x reference)
//
#include <hip/hip_runtime.h>

// out[b, s*3+c, ph, pw] = img[c, (ys[b*2+s]+ph)&4095, (xs[b*2+s]+pw)&4095]
// Output flat index: ((b*6 + cc)*32 + ph)*32 + pw, cc = s*3+c.
// One thread per float4 of output (4 consecutive pw).

__global__ __launch_bounds__(256) void patch_gather_kernel(
    const float* __restrict__ img,
    const int*   __restrict__ ys,
    const int*   __restrict__ xs,
    float*       __restrict__ out)
{
    const int tid  = blockIdx.x * 256 + threadIdx.x;
    const int flat = tid * 4;                 // output flat element index

    const int pw0 = flat & 31;                // 0,4,8,...,28
    const int ph  = (flat >> 5) & 31;
    const int t   = flat >> 10;               // b*6 + cc, in [0, 1536)
    const int b   = t / 6;                    // compiler: magic-mul
    const int cc  = t - b * 6;                // s*3 + c
    const int s   = (cc >= 3) ? 1 : 0;
    const int c   = cc - s * 3;
    const int n   = b * 2 + s;

    const int y     = (ys[n] + ph) & 4095;
    const int xbase = xs[n] + pw0;

    const float* __restrict__ row = img + ((size_t)c * 4096 + (size_t)y) * 4096;

    float4 v;
    v.x = row[(xbase    ) & 4095];
    v.y = row[(xbase + 1) & 4095];
    v.z = row[(xbase + 2) & 4095];
    v.w = row[(xbase + 3) & 4095];

    *reinterpret_cast<float4*>(out + flat) = v;
}

extern "C" void kernel_launch(void* const* d_in, const int* in_sizes, int n_in,
                              void* d_out, int out_size, void* d_ws, size_t ws_size,
                              hipStream_t stream)
{
    const float* img = (const float*)d_in[0];   // [1,3,4096,4096] fp32
    const int*   ys  = (const int*)d_in[1];     // [512]
    const int*   xs  = (const int*)d_in[2];     // [512]
    float*       out = (float*)d_out;           // [256,6,32,32] fp32

    const int n_vec  = out_size / 4;            // 393216
    const int blocks = (n_vec + 255) / 256;     // 1536

    patch_gather_kernel<<<blocks, 256, 0, stream>>>(img, ys, xs, out);
}